// Round 5
// baseline (2860.256 us; speedup 1.0000x reference)
//
#include <hip/hip_runtime.h>
#include <hip/hip_bf16.h>

// Problem constants
#define B_   2048   // batch
#define E_   512    // embedding / hidden
#define S_   64     // sequence length
#define K_   1024   // fused GEMM K = E (x part) + E (h part)
#define NG   2048   // 4*E gate rows

#define BM 128
#define BN 128
#define BK 32
#define ND 5        // LDS ring depth (prefetch distance 4)

typedef __attribute__((ext_vector_type(8))) short  bfrag8;
typedef __attribute__((ext_vector_type(4))) float  f32x4;

#define WAITVM(N) asm volatile("s_waitcnt vmcnt(" #N ")" ::: "memory")

__device__ __forceinline__ void gload16(const void* g, void* l) {
  __builtin_amdgcn_global_load_lds(
      (const __attribute__((address_space(1))) unsigned int*)g,
      (__attribute__((address_space(3))) unsigned int*)l,
      16, 0, 0);
}

__device__ __forceinline__ float sigm(float x)      { return 1.f / (1.f + __expf(-x)); }
__device__ __forceinline__ float tanh_fast(float x) { return 2.f / (1.f + __expf(-2.f * x)) - 1.f; }

// Gate-interleaved permutation (verified by absmax pass rounds 1-4).
// Permuted row p: te = p>>7, c = p&127 = hi*64 + g*16 + q
//   e = te*32 + hi*16 + q ; original gate row n = g*512 + e
__global__ __launch_bounds__(256) void prep_weights(
    const float* __restrict__ Wih, const float* __restrict__ Whh,
    const float* __restrict__ bih, const float* __restrict__ bhh,
    __hip_bfloat16* __restrict__ Wp, float* __restrict__ biasP)
{
  int p  = blockIdx.x;
  int te = p >> 7;
  int c  = p & 127;
  int hi = (c >> 6) & 1;
  int g  = (c >> 4) & 3;
  int q  = c & 15;
  int e  = te * 32 + hi * 16 + q;
  int n  = g * E_ + e;
  const float* s0 = Wih + (size_t)n * E_;
  const float* s1 = Whh + (size_t)n * E_;
  __hip_bfloat16* dst = Wp + (size_t)p * K_;
  for (int k = threadIdx.x; k < E_; k += 256) {
    dst[k]       = __float2bfloat16(s0[k]);
    dst[E_ + k]  = __float2bfloat16(s1[k]);
  }
  if (threadIdx.x == 0) biasP[p] = bih[n] + bhh[n];
}

// A0[b][0:512] = bf16(emb[x[b][0]]); A0[b][512:1024] = 0; zero barrier counters
__global__ __launch_bounds__(256) void init_state(
    const int* __restrict__ x, const float* __restrict__ emb,
    __hip_bfloat16* __restrict__ A0, unsigned* __restrict__ bar)
{
  int b  = blockIdx.x;
  int xi = x[(size_t)b * S_ + 0];
  const float* e = emb + (size_t)xi * E_;
  __hip_bfloat16* a = A0 + (size_t)b * K_;
  for (int k = threadIdx.x; k < E_; k += 256) {
    a[k]       = __float2bfloat16(e[k]);
    a[E_ + k]  = __float2bfloat16(0.f);
  }
  if (b == 0 && threadIdx.x < 16) bar[threadIdx.x] = 0;   // re-zeroed every launch
}

// Persistent LSTM: 256 blocks x 256 thr (4 waves, wave=64x64), all 64 steps.
// Per-tm-group (16 blocks) barrier between steps. c-state in registers.
// LDS chunk-swizzle: chunk' = chunk ^ ((chunk>>3)&7)  (16B chunks; <=2-way banks)
__global__ __launch_bounds__(256, 2) void lstm_persist(
    const __hip_bfloat16* __restrict__ Wp,     // [2048][1024] bf16 permuted
    const float* __restrict__ biasP,           // [2048]
    __hip_bfloat16* __restrict__ A0,           // [2048][1024] bf16 (t even src)
    __hip_bfloat16* __restrict__ A1,           // [2048][1024] bf16
    const int* __restrict__ x,                 // [2048][64] int32
    const float* __restrict__ emb,             // [32000][512] fp32
    float* __restrict__ out,                   // [2048][512] fp32
    unsigned* __restrict__ bar)                // [16] group barrier counters
{
  __shared__ __hip_bfloat16 As[ND][BM * BK];   // 5 x 8 KB
  __shared__ __hip_bfloat16 Bs[ND][BN * BK];   // 5 x 8 KB  (81920 B total)

  const int tid = threadIdx.x;
  // XCD-chunked: per XCD 8 tm x 4 te
  const int x7 = blockIdx.x & 7;
  const int ii = blockIdx.x >> 3;              // 0..31
  const int tm = (x7 & 1) * 8 + (ii & 7);      // 0..15
  const int te = (x7 >> 1) * 4 + (ii >> 3);    // 0..15

  const int w  = tid >> 6, l = tid & 63;
  const int wr = w >> 1,  wc = w & 1;
  const int lq = l & 15,  lh = l >> 4;

  const int arow0 = tm * BM;
  const int brow0 = te * BN;
  const int e     = te * 32 + wc * 16 + lq;

  float bg[4];
#pragma unroll
  for (int n = 0; n < 4; ++n)
    bg[n] = biasP[te * 128 + wc * 64 + n * 16 + lq];

  // fragment LDS offsets (swizzled); residual <=2-way conflict
  int aoff[4], boff[4];
#pragma unroll
  for (int m = 0; m < 4; ++m) {
    int R = wr * 64 + m * 16 + lq;
    int cl = R * 4 + lh;
    aoff[m] = (cl ^ ((cl >> 3) & 7)) * 8;
  }
#pragma unroll
  for (int n = 0; n < 4; ++n) {
    int R = wc * 64 + n * 16 + lq;
    int cl = R * 4 + lh;
    boff[n] = (cl ^ ((cl >> 3) & 7)) * 8;
  }

  float cc[4][4];                              // cell state, registers, all steps
#pragma unroll
  for (int m = 0; m < 4; ++m)
#pragma unroll
    for (int r = 0; r < 4; ++r) cc[m][r] = 0.f;

  // stage: dest chunk ch (linear, gload_lds rule); content = inverse-swizzled src
  auto stageA = [&](const __hip_bfloat16* Acur, int kt, int buf) {
    const int k0 = kt * BK;
#pragma unroll
    for (int it = 0; it < 2; ++it) {
      int ch = it * 256 + tid;                 // 0..511
      int cl = ch ^ ((ch >> 3) & 7);
      int row = cl >> 2, gr = cl & 3;
      gload16(Acur + (size_t)(arow0 + row) * K_ + k0 + gr * 8, &As[buf][ch * 8]);
    }
  };
  auto stageB = [&](int kt, int buf) {
    const int k0 = kt * BK;
#pragma unroll
    for (int it = 0; it < 2; ++it) {
      int ch = it * 256 + tid;
      int cl = ch ^ ((ch >> 3) & 7);
      int row = cl >> 2, gr = cl & 3;
      gload16(Wp + (size_t)(brow0 + row) * K_ + k0 + gr * 8, &Bs[buf][ch * 8]);
    }
  };

  f32x4 acc[4][4];
  auto mfma_iter = [&](int rb) {
    bfrag8 af[4], bfr[4];
    const __hip_bfloat16* Ab = &As[rb][0];
    const __hip_bfloat16* Bb = &Bs[rb][0];
#pragma unroll
    for (int m = 0; m < 4; ++m) af[m]  = *(const bfrag8*)(Ab + aoff[m]);
#pragma unroll
    for (int n = 0; n < 4; ++n) bfr[n] = *(const bfrag8*)(Bb + boff[n]);
    __builtin_amdgcn_s_setprio(1);
#pragma unroll
    for (int m = 0; m < 4; ++m)
#pragma unroll
      for (int n = 0; n < 4; ++n)
        acc[m][n] = __builtin_amdgcn_mfma_f32_16x16x32_bf16(af[m], bfr[n], acc[m][n], 0, 0, 0);
    __builtin_amdgcn_s_setprio(0);
  };

#define SBAR() do { __builtin_amdgcn_s_barrier(); __builtin_amdgcn_sched_barrier(0); } while (0)

  // pre-loop: B tiles 0..3 into bufs 0..3 (8 loads; B is step-invariant)
  stageB(0, 0); stageB(1, 1); stageB(2, 2); stageB(3, 3);
  __builtin_amdgcn_sched_barrier(0);

#pragma unroll 1
  for (int t = 0; t < S_; ++t) {
    const __hip_bfloat16* Ac = (t & 1) ? A1 : A0;
    __hip_bfloat16*       An = (t & 1) ? A0 : A1;
    const bool last = (t == S_ - 1);
    const int  tn   = last ? S_ - 1 : t + 1;

    // prologue: xiv (16 loads) then A tiles 0..3 (8 loads)
    int xiv[4][4];
#pragma unroll
    for (int m = 0; m < 4; ++m)
#pragma unroll
      for (int r = 0; r < 4; ++r) {
        int b = tm * BM + wr * 64 + m * 16 + lh * 4 + r;
        xiv[m][r] = x[(size_t)b * S_ + tn];
      }
    __builtin_amdgcn_sched_barrier(0);
    stageA(Ac, 0, 0); stageA(Ac, 1, 1); stageA(Ac, 2, 2); stageA(Ac, 3, 3);
    __builtin_amdgcn_sched_barrier(0);

#pragma unroll
    for (int m = 0; m < 4; ++m)
#pragma unroll
      for (int n = 0; n < 4; ++n)
        acc[m][n] = (f32x4){0.f, 0.f, 0.f, 0.f};

    // K-loop. vmcnt ledger (per-thread loads): prologue queue [xiv16, A0..A3=8]
    // (t=0 additionally has B(8) in front -> WAITVM(6) covers them too.)
    WAITVM(6);  SBAR(); stageA(Ac, 4, 4); stageB(4, 4); mfma_iter(0);   // +t4(4)
    WAITVM(8);  SBAR(); stageA(Ac, 5, 0); stageB(5, 0); mfma_iter(1);   // +t5
    WAITVM(10); SBAR(); stageA(Ac, 6, 1); stageB(6, 1); mfma_iter(2);   // +t6
    WAITVM(12); SBAR(); stageA(Ac, 7, 2); stageB(7, 2); mfma_iter(3);   // +t7
    // ev addresses: first use of xiv after 24 in-flight loads (auto-wait is free)
    int eoff[4][4];
#pragma unroll
    for (int m = 0; m < 4; ++m)
#pragma unroll
      for (int r = 0; r < 4; ++r) eoff[m][r] = xiv[m][r] * E_ + e;

    int rb = 4, sb = 3;
#pragma unroll 1
    for (int kt = 4; kt <= 27; ++kt) {
      WAITVM(12); SBAR();
      stageA(Ac, kt + 4, sb); stageB(kt + 4, sb);
      mfma_iter(rb);
      rb = (rb == ND - 1) ? 0 : rb + 1;
      sb = (sb == ND - 1) ? 0 : sb + 1;
    }
    // tail: tiles 28..31 in bufs 3,4,0,1. Re-stage next-step B 0..3 into freed bufs.
    float ev[4][4];
    WAITVM(12); SBAR();                         // t28 done; queue [t29 t30 t31]=12
#pragma unroll
    for (int m = 0; m < 4; ++m)
#pragma unroll
      for (int r = 0; r < 4; ++r) ev[m][r] = emb[(size_t)eoff[m][r]];   // +16
    stageB(2, 2);                               // buf2 free (last read kt=27)  +2
    mfma_iter(3);
    WAITVM(26); SBAR();                         // t29 done; [t30 t31 ev Bn2]=26
    stageB(3, 3);                               // buf3 free (kt=28 read done)  +2
    mfma_iter(4);
    WAITVM(24); SBAR();                         // t30 done; [t31 ev Bn2 Bn3]=24
    mfma_iter(0);
    WAITVM(20); SBAR();                         // t31 done; [ev Bn2 Bn3]=20
    stageB(0, 0);                               // buf0 free (kt=30 read done)  +2
    mfma_iter(1);
    __syncthreads();
    stageB(1, 1);                               // buf1 free (kt=31 read done)  +2
    WAITVM(8);                                  // ev done; [Bn2 Bn3 Bn0 Bn1]=8

    // register epilogue
#pragma unroll
    for (int m = 0; m < 4; ++m) {
#pragma unroll
      for (int r = 0; r < 4; ++r) {
        int b = tm * BM + wr * 64 + m * 16 + lh * 4 + r;
        float iv = acc[m][0][r] + bg[0];
        float fv = acc[m][1][r] + bg[1];
        float gv = acc[m][2][r] + bg[2];
        float ov = acc[m][3][r] + bg[3];
        float ig = sigm(iv), fg = sigm(fv), gg = tanh_fast(gv), og = sigm(ov);
        float cn = fg * cc[m][r] + ig * gg;
        cc[m][r] = cn;
        float h = og * tanh_fast(cn);
        if (last) {
          out[(size_t)b * E_ + e] = h;
        } else {
          An[(size_t)b * K_ + E_ + e] = __float2bfloat16(h);
          An[(size_t)b * K_ + e]      = __float2bfloat16(ev[m][r]);
        }
      }
    }

    if (!last) {
      // group barrier: tm-group (16 blocks) must all finish step t
      WAITVM(0);                 // drain own stores (and Bn loads -> already in LDS)
      __syncthreads();
      if (tid == 0) {
        __threadfence();         // release: wbL2 so other XCDs see An
        atomicAdd(&bar[tm], 1u);
        unsigned target = 16u * (unsigned)(t + 1);
        int guard = 0;
        while (__hip_atomic_load(&bar[tm], __ATOMIC_RELAXED, __HIP_MEMORY_SCOPE_AGENT) < target
               && ++guard < (1 << 26)) {
          __builtin_amdgcn_s_sleep(1);
        }
        __threadfence();         // acquire: inv caches before reading An
      }
      __syncthreads();
    }
  }
#undef SBAR
}

extern "C" void kernel_launch(void* const* d_in, const int* in_sizes, int n_in,
                              void* d_out, int out_size, void* d_ws, size_t ws_size,
                              hipStream_t stream) {
  const int*   x   = (const int*)d_in[0];
  const float* emb = (const float*)d_in[1];
  const float* Wih = (const float*)d_in[2];
  const float* Whh = (const float*)d_in[3];
  const float* bih = (const float*)d_in[4];
  const float* bhh = (const float*)d_in[5];
  float* out = (float*)d_out;
  (void)in_sizes; (void)n_in; (void)out_size; (void)ws_size;

  char* p = (char*)d_ws;
  __hip_bfloat16* Wp    = (__hip_bfloat16*)p;  p += (size_t)NG * K_ * 2;  // 4 MB
  float*          biasP = (float*)p;           p += (size_t)NG * 4;       // 8 KB
  __hip_bfloat16* A0    = (__hip_bfloat16*)p;  p += (size_t)B_ * K_ * 2;  // 4 MB
  __hip_bfloat16* A1    = (__hip_bfloat16*)p;  p += (size_t)B_ * K_ * 2;  // 4 MB
  unsigned*       bar   = (unsigned*)p;        p += 64;

  prep_weights<<<NG, 256, 0, stream>>>(Wih, Whh, bih, bhh, Wp, biasP);
  init_state<<<B_, 256, 0, stream>>>(x, emb, A0, bar);
  lstm_persist<<<256, 256, 0, stream>>>(Wp, biasP, A0, A1, x, emb, out, bar);
}

// Round 6
// 2436.236 us; speedup vs baseline: 1.1740x; 1.1740x over previous
//
#include <hip/hip_runtime.h>
#include <hip/hip_bf16.h>

// Problem constants
#define B_   2048
#define E_   512
#define S_   64
#define K_   1024
#define NG   2048

#define BM 128
#define BN 64
#define BK 32
#define ND 4        // LDS ring depth (stage distance 3)

typedef __attribute__((ext_vector_type(8))) short  bfrag8;
typedef __attribute__((ext_vector_type(4))) float  f32x4;

#define WAITVM(N) asm volatile("s_waitcnt vmcnt(" #N ")" ::: "memory")

__device__ __forceinline__ void gload16(const void* g, void* l) {
  __builtin_amdgcn_global_load_lds(
      (const __attribute__((address_space(1))) unsigned int*)g,
      (__attribute__((address_space(3))) unsigned int*)l,
      16, 0, 0);
}

__device__ __forceinline__ float sigm(float x)      { return 1.f / (1.f + __expf(-x)); }
__device__ __forceinline__ float tanh_fast(float x) { return 2.f / (1.f + __expf(-2.f * x)) - 1.f; }

// Gate-interleaved permutation for BN=64: p = te*64 + g*16 + q
//   e = te*16 + q ; original gate row n = g*512 + e
// Wp[p][0:512]=W_ih[n][:], Wp[p][512:1024]=W_hh[n][:]  (bf16)
__global__ __launch_bounds__(256) void prep_weights(
    const float* __restrict__ Wih, const float* __restrict__ Whh,
    const float* __restrict__ bih, const float* __restrict__ bhh,
    __hip_bfloat16* __restrict__ Wp, float* __restrict__ biasP)
{
  int p  = blockIdx.x;
  int te = p >> 6;
  int c  = p & 63;
  int g  = c >> 4;
  int q  = c & 15;
  int e  = te * 16 + q;
  int n  = g * E_ + e;
  const float* s0 = Wih + (size_t)n * E_;
  const float* s1 = Whh + (size_t)n * E_;
  __hip_bfloat16* dst = Wp + (size_t)p * K_;
  for (int k = threadIdx.x; k < E_; k += 256) {
    dst[k]       = __float2bfloat16(s0[k]);
    dst[E_ + k]  = __float2bfloat16(s1[k]);
  }
  if (threadIdx.x == 0) biasP[p] = bih[n] + bhh[n];
}

// Xe[t][b][e] = bf16(emb[x[b][t]][e])  -- one-time gather, 128 MB
__global__ __launch_bounds__(256) void pregather(
    const int* __restrict__ x, const float* __restrict__ emb,
    __hip_bfloat16* __restrict__ Xe)
{
  int row  = blockIdx.x * 4 + (threadIdx.x >> 6);   // row = b*64 + t
  int lane = threadIdx.x & 63;
  int b = row >> 6, t = row & 63;
  size_t xi = (size_t)x[row];
  const float* src = emb + xi * E_ + lane * 8;
  float4 f0 = *(const float4*)(src);
  float4 f1 = *(const float4*)(src + 4);
  union { __hip_bfloat16 h[8]; uint4 v; } u;
  u.h[0] = __float2bfloat16(f0.x); u.h[1] = __float2bfloat16(f0.y);
  u.h[2] = __float2bfloat16(f0.z); u.h[3] = __float2bfloat16(f0.w);
  u.h[4] = __float2bfloat16(f1.x); u.h[5] = __float2bfloat16(f1.y);
  u.h[6] = __float2bfloat16(f1.z); u.h[7] = __float2bfloat16(f1.w);
  *(uint4*)(Xe + ((size_t)t * B_ + b) * E_ + lane * 8) = u.v;
}

// Persistent LSTM: 512 blocks x 128 thr (2 waves, each 64 rows x 64 cols).
// A = [Xe[t] | H], staged tile-by-tile; h-half gated by per-tm group barrier
// placed at iter 12 so the xe-half GEMM overlaps the wait + L2 refill.
__global__ __launch_bounds__(128, 2) void lstm_persist(
    const __hip_bfloat16* __restrict__ Wp,     // [2048][1024]
    const float* __restrict__ biasP,           // [2048]
    const __hip_bfloat16* __restrict__ Xe,     // [64][2048][512]
    __hip_bfloat16* __restrict__ H0,           // [2048][512] (zeroed)
    __hip_bfloat16* __restrict__ H1,           // [2048][512]
    float* __restrict__ out,                   // [2048][512]
    unsigned* __restrict__ bar)                // [16]
{
  __shared__ __hip_bfloat16 As[ND][BM * BK];   // 4 x 8 KB
  __shared__ __hip_bfloat16 Bs[ND][BN * BK];   // 4 x 4 KB  (48 KB total)

  const int tid = threadIdx.x;
  // XCD-chunked: each XCD gets 4 tm x 16 te (H-slice 512KB, Wp-slice 2MB)
  const int x7 = blockIdx.x & 7;
  const int ii = blockIdx.x >> 3;              // 0..63
  const int tm = (x7 >> 1) * 4 + (ii & 3);     // 0..15
  const int te = (x7 & 1) * 16 + (ii >> 2);    // 0..31

  const int w  = tid >> 6, l = tid & 63;
  const int lq = l & 15,  lh = l >> 4;

  const int arow0 = tm * BM;
  const int brow0 = te * BN;
  const int e     = te * 16 + lq;

  float bg[4];
#pragma unroll
  for (int n = 0; n < 4; ++n)
    bg[n] = biasP[te * 64 + n * 16 + lq];

  // fragment LDS chunk offsets (chunk swizzle cl^((cl>>3)&7), verified 0-conflict)
  int aoff[4], boff[4];
#pragma unroll
  for (int m = 0; m < 4; ++m) {
    int R  = w * 64 + m * 16 + lq;
    int cl = R * 4 + lh;
    aoff[m] = (cl ^ ((cl >> 3) & 7)) * 8;
  }
#pragma unroll
  for (int n = 0; n < 4; ++n) {
    int R  = n * 16 + lq;
    int cl = R * 4 + lh;
    boff[n] = (cl ^ ((cl >> 3) & 7)) * 8;
  }

  float cc[4][4];
#pragma unroll
  for (int m = 0; m < 4; ++m)
#pragma unroll
    for (int r = 0; r < 4; ++r) cc[m][r] = 0.f;

  // staging: dest chunk ch linear (gload_lds rule); source chunk = swz(ch)
  auto stageA_xe = [&](int tt, int kt, int buf) {
    const int k0 = kt * BK;
#pragma unroll
    for (int it = 0; it < 4; ++it) {
      int ch = it * 128 + tid;                 // 0..511
      int cl = ch ^ ((ch >> 3) & 7);
      int row = cl >> 2, gr = cl & 3;
      gload16(Xe + ((size_t)tt * B_ + arow0 + row) * E_ + k0 + gr * 8,
              &As[buf][ch * 8]);
    }
  };
  auto stageA_h = [&](const __hip_bfloat16* H, int kt, int buf) {
    const int k0 = (kt - 16) * BK;
#pragma unroll
    for (int it = 0; it < 4; ++it) {
      int ch = it * 128 + tid;
      int cl = ch ^ ((ch >> 3) & 7);
      int row = cl >> 2, gr = cl & 3;
      gload16(H + (size_t)(arow0 + row) * E_ + k0 + gr * 8, &As[buf][ch * 8]);
    }
  };
  auto stageB = [&](int kt, int buf) {
    const int k0 = kt * BK;
#pragma unroll
    for (int it = 0; it < 2; ++it) {
      int ch = it * 128 + tid;                 // 0..255
      int cl = ch ^ ((ch >> 3) & 7);
      int row = cl >> 2, gr = cl & 3;
      gload16(Wp + (size_t)(brow0 + row) * K_ + k0 + gr * 8, &Bs[buf][ch * 8]);
    }
  };

  f32x4 acc[4][4];
  auto mfma_iter = [&](int rb) {
    bfrag8 af[4], bfr[4];
    const __hip_bfloat16* Ab = &As[rb][0];
    const __hip_bfloat16* Bb = &Bs[rb][0];
#pragma unroll
    for (int m = 0; m < 4; ++m) af[m]  = *(const bfrag8*)(Ab + aoff[m]);
#pragma unroll
    for (int n = 0; n < 4; ++n) bfr[n] = *(const bfrag8*)(Bb + boff[n]);
    __builtin_amdgcn_s_setprio(1);
#pragma unroll
    for (int m = 0; m < 4; ++m)
#pragma unroll
      for (int n = 0; n < 4; ++n)
        acc[m][n] = __builtin_amdgcn_mfma_f32_16x16x32_bf16(af[m], bfr[n], acc[m][n], 0, 0, 0);
    __builtin_amdgcn_s_setprio(0);
  };

  // prologue: tiles 0,1,2 (xe) for step 0
  stageA_xe(0, 0, 0); stageB(0, 0);
  stageA_xe(0, 1, 1); stageB(1, 1);
  stageA_xe(0, 2, 2); stageB(2, 2);
  __builtin_amdgcn_sched_barrier(0);

#pragma unroll 1
  for (int t = 0; t < S_; ++t) {
    const __hip_bfloat16* Hprev = (t & 1) ? H1 : H0;
    __hip_bfloat16*       Hnext = (t & 1) ? H0 : H1;
    const int tt_next = (t < S_ - 1) ? t + 1 : S_ - 1;

#pragma unroll
    for (int m = 0; m < 4; ++m)
#pragma unroll
      for (int n = 0; n < 4; ++n)
        acc[m][n] = (f32x4){0.f, 0.f, 0.f, 0.f};

    // 32 K-iterations; ledger: 6 loads/iter, ring ND=4, stage(kt+3) at iter kt.
    // At iter kt: outstanding <= tiles kt..kt+2 (18); WAITVM(12) => tile kt done.
#pragma unroll 1
    for (int kt = 0; kt < 32; ++kt) {
      WAITVM(12);
      __builtin_amdgcn_s_barrier();
      __builtin_amdgcn_sched_barrier(0);
      if (kt == 12) {
        // last xe tile, then the h barrier + acquire (overlapped by iters 0-12)
        stageA_xe(t, 15, 15 & 3); stageB(15, 15 & 3);
        unsigned target = 32u * (unsigned)t;
        int guard = 0;
        while (__hip_atomic_load(bar + tm, __ATOMIC_RELAXED,
                                 __HIP_MEMORY_SCOPE_AGENT) < target
               && ++guard < (1 << 24))
          __builtin_amdgcn_s_sleep(2);
        __builtin_amdgcn_fence(__ATOMIC_ACQUIRE, "agent");   // inv; drains vmcnt
        __builtin_amdgcn_sched_barrier(0);
      } else {
        int gt = kt + 3;
        if (gt < 16)      { stageA_xe(t, gt, gt & 3);        stageB(gt, gt & 3); }
        else if (gt < 32) { stageA_h(Hprev, gt, gt & 3);     stageB(gt, gt & 3); }
        else              { stageA_xe(tt_next, gt - 32, gt & 3); stageB(gt - 32, gt & 3); }
      }
      mfma_iter(kt & 3);
    }

    // epilogue: register cell update
    const bool last = (t == S_ - 1);
#pragma unroll
    for (int m = 0; m < 4; ++m) {
#pragma unroll
      for (int r = 0; r < 4; ++r) {
        int b = tm * BM + w * 64 + m * 16 + lh * 4 + r;
        float iv = acc[m][0][r] + bg[0];
        float fv = acc[m][1][r] + bg[1];
        float gv = acc[m][2][r] + bg[2];
        float ov = acc[m][3][r] + bg[3];
        float ig = sigm(iv), fg = sigm(fv), gg = tanh_fast(gv), og = sigm(ov);
        float cn = fg * cc[m][r] + ig * gg;
        cc[m][r] = cn;
        float h = og * tanh_fast(cn);
        if (last) out[(size_t)b * E_ + e] = h;
        else      Hnext[(size_t)b * E_ + e] = __float2bfloat16(h);
      }
    }

    if (!last) {
      WAITVM(0);                       // all stores (and prefetches) complete
      __syncthreads();
      if (tid == 0) {
        __builtin_amdgcn_fence(__ATOMIC_RELEASE, "agent");   // wbl2 (no inv)
        atomicAdd(bar + tm, 1u);
      }
      __syncthreads();
    }
  }
}

extern "C" void kernel_launch(void* const* d_in, const int* in_sizes, int n_in,
                              void* d_out, int out_size, void* d_ws, size_t ws_size,
                              hipStream_t stream) {
  const int*   x   = (const int*)d_in[0];
  const float* emb = (const float*)d_in[1];
  const float* Wih = (const float*)d_in[2];
  const float* Whh = (const float*)d_in[3];
  const float* bih = (const float*)d_in[4];
  const float* bhh = (const float*)d_in[5];
  float* out = (float*)d_out;
  (void)in_sizes; (void)n_in; (void)out_size; (void)ws_size;

  char* p = (char*)d_ws;
  __hip_bfloat16* Wp    = (__hip_bfloat16*)p;  p += (size_t)NG * K_ * 2;        // 4 MB
  float*          biasP = (float*)p;           p += (size_t)NG * 4;             // 8 KB
  __hip_bfloat16* Xe    = (__hip_bfloat16*)p;  p += (size_t)S_ * B_ * E_ * 2;   // 128 MB
  __hip_bfloat16* H0    = (__hip_bfloat16*)p;  p += (size_t)B_ * E_ * 2;        // 2 MB
  __hip_bfloat16* H1    = (__hip_bfloat16*)p;  p += (size_t)B_ * E_ * 2;        // 2 MB
  unsigned*       bar   = (unsigned*)p;        p += 64;

  prep_weights<<<NG, 256, 0, stream>>>(Wih, Whh, bih, bhh, Wp, biasP);
  pregather<<<(B_ * S_) / 4, 256, 0, stream>>>(x, emb, Xe);
  hipMemsetAsync(H0, 0, (size_t)B_ * E_ * 2, stream);
  hipMemsetAsync(bar, 0, 64, stream);
  lstm_persist<<<512, 128, 0, stream>>>(Wp, biasP, Xe, H0, H1, out, bar);
}

// Round 7
// 1582.699 us; speedup vs baseline: 1.8072x; 1.5393x over previous
//
#include <hip/hip_runtime.h>
#include <hip/hip_bf16.h>

// Problem constants
#define B_   2048   // batch
#define E_   512    // embedding / hidden
#define S_   64     // sequence length
#define K_   1024   // fused GEMM K = E (x part) + E (h part)
#define NG   2048   // 4*E gate rows

#define BM 64
#define BN 128
#define BK 32
#define ND  5         // LDS ring depth (prefetch distance 4)

typedef __attribute__((ext_vector_type(8))) short  bfrag8;
typedef __attribute__((ext_vector_type(4))) float  f32x4;

#define WAITVM(N) asm volatile("s_waitcnt vmcnt(" #N ")" ::: "memory")

__device__ __forceinline__ void gload16(const void* g, void* l) {
  __builtin_amdgcn_global_load_lds(
      (const __attribute__((address_space(1))) unsigned int*)g,
      (__attribute__((address_space(3))) unsigned int*)l,
      16, 0, 0);
}

__device__ __forceinline__ float sigm(float x)      { return 1.f / (1.f + __expf(-x)); }
__device__ __forceinline__ float tanh_fast(float x) { return 2.f / (1.f + __expf(-2.f * x)) - 1.f; }

// Gate-interleaved permutation (verified rounds 1-6).
// Permuted row p: te = p>>7, c = p&127 = hi*64 + g*16 + q
//   e = te*32 + hi*16 + q ; original gate row n = g*512 + e
__global__ __launch_bounds__(256) void prep_weights(
    const float* __restrict__ Wih, const float* __restrict__ Whh,
    const float* __restrict__ bih, const float* __restrict__ bhh,
    __hip_bfloat16* __restrict__ Wp, float* __restrict__ biasP)
{
  int p  = blockIdx.x;
  int te = p >> 7;
  int c  = p & 127;
  int hi = (c >> 6) & 1;
  int g  = (c >> 4) & 3;
  int q  = c & 15;
  int e  = te * 32 + hi * 16 + q;
  int n  = g * E_ + e;
  const float* s0 = Wih + (size_t)n * E_;
  const float* s1 = Whh + (size_t)n * E_;
  __hip_bfloat16* dst = Wp + (size_t)p * K_;
  for (int k = threadIdx.x; k < E_; k += 256) {
    dst[k]       = __float2bfloat16(s0[k]);
    dst[E_ + k]  = __float2bfloat16(s1[k]);
  }
  if (threadIdx.x == 0) biasP[p] = bih[n] + bhh[n];
}

// c = 0; A0[b][0:512] = bf16(emb[x[b][0]]); A0[b][512:1024] = 0 (h0 = 0)
__global__ __launch_bounds__(256) void init_state(
    const int* __restrict__ x, const float* __restrict__ emb,
    float* __restrict__ c, __hip_bfloat16* __restrict__ A0)
{
  int b  = blockIdx.x;
  int xi = x[(size_t)b * S_ + 0];
  const float* e = emb + (size_t)xi * E_;
  __hip_bfloat16* a = A0 + (size_t)b * K_;
  float* cr = c + (size_t)b * E_;
  for (int k = threadIdx.x; k < E_; k += 256) {
    a[k]       = __float2bfloat16(e[k]);
    a[E_ + k]  = __float2bfloat16(0.f);
    cr[k]      = 0.f;
  }
}

// One fused LSTM timestep. 2 waves/block, wave = 64x64 (acc[4][4]).
// Counted-vmcnt 5-deep pipeline; VERIFIED chunk-swizzle (r5/r6: 0 conflicts):
//   chunk' = chunk ^ ((chunk>>3)&7)   (16B chunks; involution)
__global__ __launch_bounds__(128) void lstm_step(
    const __hip_bfloat16* __restrict__ Acur,   // [2048][1024] bf16
    __hip_bfloat16* __restrict__ Anext,        // [2048][1024] bf16
    const __hip_bfloat16* __restrict__ Wp,     // [2048][1024] bf16 (permuted)
    const float* __restrict__ biasP,           // [2048] permuted
    float* __restrict__ c,                     // [2048][512] fp32
    const int* __restrict__ x,                 // [2048][64] int32
    const float* __restrict__ emb,             // [32000][512] fp32
    float* __restrict__ out,                   // [2048][512] fp32
    int t)
{
  __shared__ __hip_bfloat16 As[ND][BM * BK];   // 5 x 4 KB
  __shared__ __hip_bfloat16 Bs[ND][BN * BK];   // 5 x 8 KB

  const int tid = threadIdx.x;
  // XCD-chunked 2D swizzle (per-XCD: 16 tm x 4 te; Wp slice 1 MB step-invariant)
  const int x7 = blockIdx.x & 7;
  const int i  = blockIdx.x >> 3;
  const int tm = (x7 & 1) * 16 + (i & 15);
  const int te = (x7 >> 1) * 4 + (i >> 4);

  const int wc = tid >> 6;
  const int l  = tid & 63;
  const int lq = l & 15;
  const int lh = l >> 4;

  const int arow0 = tm * BM;
  const int brow0 = te * BN;

  // ---- prefetches (issued before the GEMM pipeline) ----
  float bg[4];
#pragma unroll
  for (int n = 0; n < 4; ++n)
    bg[n] = biasP[te * 128 + wc * 64 + n * 16 + lq];

  const int e = te * 32 + wc * 16 + lq;
  float cold[4][4];
  int   xiv[4][4];
  const int tn = (t < S_ - 1) ? t + 1 : S_ - 1;
#pragma unroll
  for (int m = 0; m < 4; ++m)
#pragma unroll
    for (int r = 0; r < 4; ++r) {
      int b = tm * BM + m * 16 + lh * 4 + r;
      cold[m][r] = c[(size_t)b * E_ + e];
      xiv[m][r]  = x[(size_t)b * S_ + tn];
    }
  __builtin_amdgcn_sched_barrier(0);

  // stage: dest chunk ch linear (gload_lds rule); content = swizzled source chunk
  auto stage = [&](int kt, int buf) {
    const int k0 = kt * BK;
    // A tile: 64 rows x 64 B = 256 chunks; 2 per thread
#pragma unroll
    for (int it = 0; it < 2; ++it) {
      int ch  = it * 128 + tid;                // 0..255
      int cl  = ch ^ ((ch >> 3) & 7);
      int row = cl >> 2, gr = cl & 3;
      gload16(Acur + (size_t)(arow0 + row) * K_ + k0 + gr * 8, &As[buf][ch * 8]);
    }
    // B tile: 128 rows x 64 B = 512 chunks; 4 per thread
#pragma unroll
    for (int it = 0; it < 4; ++it) {
      int ch  = it * 128 + tid;                // 0..511
      int cl  = ch ^ ((ch >> 3) & 7);
      int row = cl >> 2, gr = cl & 3;
      gload16(Wp + (size_t)(brow0 + row) * K_ + k0 + gr * 8, &Bs[buf][ch * 8]);
    }
  };

  stage(0, 0);                                  // 6 loads
  __builtin_amdgcn_sched_barrier(0);
  float ev[4][4];                                // emb gather (waits xi: vmcnt leaves s0)
#pragma unroll
  for (int m = 0; m < 4; ++m)
#pragma unroll
    for (int r = 0; r < 4; ++r)
      ev[m][r] = emb[(size_t)xiv[m][r] * E_ + e];   // 16 loads
  __builtin_amdgcn_sched_barrier(0);
  stage(1, 1); stage(2, 2); stage(3, 3);        // 18 loads
  __builtin_amdgcn_sched_barrier(0);

  // ---- fragment offsets (swizzled chunk reads; verified 0-conflict) ----
  int aoff[4], boff[4];
#pragma unroll
  for (int m = 0; m < 4; ++m) {
    int cl = (m * 16 + lq) * 4 + lh;             // logical chunk in A tile
    aoff[m] = (cl ^ ((cl >> 3) & 7)) * 8;
  }
#pragma unroll
  for (int n = 0; n < 4; ++n) {
    int cl = (wc * 64 + n * 16 + lq) * 4 + lh;   // logical chunk in B tile
    boff[n] = (cl ^ ((cl >> 3) & 7)) * 8;
  }

  f32x4 acc[4][4];
#pragma unroll
  for (int m = 0; m < 4; ++m)
#pragma unroll
    for (int n = 0; n < 4; ++n)
      acc[m][n] = (f32x4){0.f, 0.f, 0.f, 0.f};

  auto mfma_iter = [&](int rb) {
    bfrag8 af[4], bfr[4];
    const __hip_bfloat16* Ab = &As[rb][0];
    const __hip_bfloat16* Bb = &Bs[rb][0];
#pragma unroll
    for (int m = 0; m < 4; ++m) af[m]  = *(const bfrag8*)(Ab + aoff[m]);
#pragma unroll
    for (int n = 0; n < 4; ++n) bfr[n] = *(const bfrag8*)(Bb + boff[n]);
    __builtin_amdgcn_s_setprio(1);
#pragma unroll
    for (int m = 0; m < 4; ++m)
#pragma unroll
      for (int n = 0; n < 4; ++n)
        acc[m][n] = __builtin_amdgcn_mfma_f32_16x16x32_bf16(af[m], bfr[n], acc[m][n], 0, 0, 0);
    __builtin_amdgcn_s_setprio(0);
  };

  // ---- counted-vmcnt pipeline ----
  // queue at kt=0: [s0(6), emb(16), s1, s2, s3]=40 -> keep 34 => s0 done
  WAITVM(34); __builtin_amdgcn_s_barrier(); __builtin_amdgcn_sched_barrier(0);
  stage(4, 4);
  mfma_iter(0);

  int rb = 1, sb = 0;
#pragma unroll 1
  for (int kt = 1; kt <= 27; ++kt) {
    WAITVM(18); __builtin_amdgcn_s_barrier(); __builtin_amdgcn_sched_barrier(0);
    stage(kt + 4, sb);
    mfma_iter(rb);
    rb = (rb == ND - 1) ? 0 : rb + 1;
    sb = (sb == ND - 1) ? 0 : sb + 1;
  }
  // tail: kt = 28..31 read bufs 3,4,0,1; no more stages
  WAITVM(18); __builtin_amdgcn_s_barrier(); __builtin_amdgcn_sched_barrier(0); mfma_iter(3);
  WAITVM(12); __builtin_amdgcn_s_barrier(); __builtin_amdgcn_sched_barrier(0); mfma_iter(4);
  WAITVM(6);  __builtin_amdgcn_s_barrier(); __builtin_amdgcn_sched_barrier(0); mfma_iter(0);
  WAITVM(0);  __builtin_amdgcn_s_barrier(); __builtin_amdgcn_sched_barrier(0); mfma_iter(1);

  // ---- register epilogue ----
  const bool last = (t == S_ - 1);
#pragma unroll
  for (int m = 0; m < 4; ++m) {
#pragma unroll
    for (int r = 0; r < 4; ++r) {
      int b = tm * BM + m * 16 + lh * 4 + r;
      float iv = acc[m][0][r] + bg[0];
      float fv = acc[m][1][r] + bg[1];
      float gv = acc[m][2][r] + bg[2];
      float ov = acc[m][3][r] + bg[3];
      size_t cidx = (size_t)b * E_ + e;
      float ig = sigm(iv), fg = sigm(fv), gg = tanh_fast(gv), og = sigm(ov);
      float cn = fg * cold[m][r] + ig * gg;
      c[cidx] = cn;
      float h = og * tanh_fast(cn);
      if (last) {
        out[cidx] = h;
      } else {
        Anext[(size_t)b * K_ + E_ + e] = __float2bfloat16(h);
        Anext[(size_t)b * K_ + e]      = __float2bfloat16(ev[m][r]);
      }
    }
  }
}

extern "C" void kernel_launch(void* const* d_in, const int* in_sizes, int n_in,
                              void* d_out, int out_size, void* d_ws, size_t ws_size,
                              hipStream_t stream) {
  const int*   x   = (const int*)d_in[0];
  const float* emb = (const float*)d_in[1];
  const float* Wih = (const float*)d_in[2];
  const float* Whh = (const float*)d_in[3];
  const float* bih = (const float*)d_in[4];
  const float* bhh = (const float*)d_in[5];
  float* out = (float*)d_out;
  (void)in_sizes; (void)n_in; (void)out_size; (void)ws_size;

  char* p = (char*)d_ws;
  __hip_bfloat16* Wp    = (__hip_bfloat16*)p;  p += (size_t)NG * K_ * 2;  // 4 MB
  float*          biasP = (float*)p;           p += (size_t)NG * 4;       // 8 KB
  float*          c     = (float*)p;           p += (size_t)B_ * E_ * 4;  // 4 MB
  __hip_bfloat16* A0    = (__hip_bfloat16*)p;  p += (size_t)B_ * K_ * 2;  // 4 MB
  __hip_bfloat16* A1    = (__hip_bfloat16*)p;  p += (size_t)B_ * K_ * 2;  // 4 MB

  prep_weights<<<NG, 256, 0, stream>>>(Wih, Whh, bih, bhh, Wp, biasP);
  init_state<<<B_, 256, 0, stream>>>(x, emb, c, A0);
  for (int t = 0; t < S_; ++t) {
    __hip_bfloat16* Ac = (t & 1) ? A1 : A0;
    __hip_bfloat16* An = (t & 1) ? A0 : A1;
    lstm_step<<<512, 128, 0, stream>>>(Ac, An, Wp, biasP, c, x, emb, out, t);
  }
}

// Round 8
// 1338.216 us; speedup vs baseline: 2.1374x; 1.1827x over previous
//
#include <hip/hip_runtime.h>
#include <hip/hip_bf16.h>

// Problem constants
#define B_   2048   // batch
#define E_   512    // embedding / hidden
#define S_   64     // sequence length
#define K_   1024   // fused GEMM K = E (x part) + E (h part)
#define NG   2048   // 4*E gate rows

#define BM 128
#define BN 128
#define BK 64
#define NKT (K_/BK)   // 16 K-tiles
#define ND  4         // LDS ring depth (prefetch distance 3)

typedef __attribute__((ext_vector_type(8))) short  bfrag8;
typedef __attribute__((ext_vector_type(4))) float  f32x4;

#define WAITVM(N) asm volatile("s_waitcnt vmcnt(" #N ")" ::: "memory")

__device__ __forceinline__ void gload16(const void* g, void* l) {
  __builtin_amdgcn_global_load_lds(
      (const __attribute__((address_space(1))) unsigned int*)g,
      (__attribute__((address_space(3))) unsigned int*)l,
      16, 0, 0);
}

__device__ __forceinline__ float sigm(float x)      { return 1.f / (1.f + __expf(-x)); }
__device__ __forceinline__ float tanh_fast(float x) { return 2.f / (1.f + __expf(-2.f * x)) - 1.f; }

// Gate-interleaved permutation (verified rounds 1-7).
// Permuted row p: te = p>>7, c = p&127 = hi*64 + g*16 + q
//   e = te*32 + hi*16 + q ; original gate row n = g*512 + e
__global__ __launch_bounds__(256) void prep_weights(
    const float* __restrict__ Wih, const float* __restrict__ Whh,
    const float* __restrict__ bih, const float* __restrict__ bhh,
    __hip_bfloat16* __restrict__ Wp, float* __restrict__ biasP)
{
  int p  = blockIdx.x;
  int te = p >> 7;
  int c  = p & 127;
  int hi = (c >> 6) & 1;
  int g  = (c >> 4) & 3;
  int q  = c & 15;
  int e  = te * 32 + hi * 16 + q;
  int n  = g * E_ + e;
  const float* s0 = Wih + (size_t)n * E_;
  const float* s1 = Whh + (size_t)n * E_;
  __hip_bfloat16* dst = Wp + (size_t)p * K_;
  for (int k = threadIdx.x; k < E_; k += 256) {
    dst[k]       = __float2bfloat16(s0[k]);
    dst[E_ + k]  = __float2bfloat16(s1[k]);
  }
  if (threadIdx.x == 0) biasP[p] = bih[n] + bhh[n];
}

// c = 0; A0[b][0:512] = bf16(emb[x[b][0]]); A0[b][512:1024] = 0 (h0 = 0)
__global__ __launch_bounds__(256) void init_state(
    const int* __restrict__ x, const float* __restrict__ emb,
    float* __restrict__ c, __hip_bfloat16* __restrict__ A0)
{
  int b  = blockIdx.x;
  int xi = x[(size_t)b * S_ + 0];
  const float* e = emb + (size_t)xi * E_;
  __hip_bfloat16* a = A0 + (size_t)b * K_;
  float* cr = c + (size_t)b * E_;
  for (int k = threadIdx.x; k < E_; k += 256) {
    a[k]       = __float2bfloat16(e[k]);
    a[E_ + k]  = __float2bfloat16(0.f);
    cr[k]      = 0.f;
  }
}

// One fused LSTM timestep. 4 waves/block (wave=64x64), 128x128 tile, BK=64:
// 16 deep-pipelined K-iterations (ND=4 ring, distance 3, counted vmcnt).
// 16B-chunk involution swizzle: cl = ch ^ ((ch>>3)&7)  (row-preserving).
__global__ __launch_bounds__(256, 1) void lstm_step(
    const __hip_bfloat16* __restrict__ Acur,   // [2048][1024] bf16
    __hip_bfloat16* __restrict__ Anext,        // [2048][1024] bf16
    const __hip_bfloat16* __restrict__ Wp,     // [2048][1024] bf16 (permuted)
    const float* __restrict__ biasP,           // [2048] permuted
    float* __restrict__ c,                     // [2048][512] fp32
    const int* __restrict__ x,                 // [2048][64] int32
    const float* __restrict__ emb,             // [32000][512] fp32
    float* __restrict__ out,                   // [2048][512] fp32
    int t)
{
  __shared__ __hip_bfloat16 As[ND][BM * BK];   // 4 x 16 KB
  __shared__ __hip_bfloat16 Bs[ND][BN * BK];   // 4 x 16 KB  (128 KB total)

  const int tid = threadIdx.x;
  // 256 blocks = 16 tm x 16 te; XCD-chunked: per XCD 8 tm x 4 te
  // (per-XCD slices: A 2 MB, Wp 1 MB step-invariant)
  const int x7 = blockIdx.x & 7;
  const int i  = blockIdx.x >> 3;              // 0..31
  const int tm = (x7 & 1) * 8 + (i & 7);       // 0..15
  const int te = (x7 >> 1) * 4 + (i >> 3);     // 0..15

  const int w  = tid >> 6, l = tid & 63;
  const int wr = w >> 1,  wc = w & 1;
  const int lq = l & 15,  lh = l >> 4;

  const int arow0 = tm * BM;
  const int brow0 = te * BN;
  const int e     = te * 32 + wc * 16 + lq;

  // ---- prologue loads: bias, cold c, next-step indices ----
  float bg[4];
#pragma unroll
  for (int n = 0; n < 4; ++n)
    bg[n] = biasP[te * 128 + wc * 64 + n * 16 + lq];

  float cold[4][4];
  int   xiv[4][4];
  const int tn = (t < S_ - 1) ? t + 1 : S_ - 1;
#pragma unroll
  for (int m = 0; m < 4; ++m)
#pragma unroll
    for (int r = 0; r < 4; ++r) {
      int b = tm * BM + wr * 64 + m * 16 + lh * 4 + r;
      cold[m][r] = c[(size_t)b * E_ + e];
      xiv[m][r]  = x[(size_t)b * S_ + tn];
    }
  __builtin_amdgcn_sched_barrier(0);

  // stage: dest chunk ch linear (gload_lds rule: base + lane*16B);
  // source = involution-swizzled chunk (row = cl>>3, k-chunk = cl&7)
  auto stageA = [&](int kt, int buf) {
    const int k0 = kt * BK;
#pragma unroll
    for (int it = 0; it < 4; ++it) {
      int ch  = it * 256 + tid;                // 0..1023
      int cl  = ch ^ ((ch >> 3) & 7);
      int row = cl >> 3, gr = cl & 7;
      gload16(Acur + (size_t)(arow0 + row) * K_ + k0 + gr * 8, &As[buf][ch * 8]);
    }
  };
  auto stageB = [&](int kt, int buf) {
    const int k0 = kt * BK;
#pragma unroll
    for (int it = 0; it < 4; ++it) {
      int ch  = it * 256 + tid;
      int cl  = ch ^ ((ch >> 3) & 7);
      int row = cl >> 3, gr = cl & 7;
      gload16(Wp + (size_t)(brow0 + row) * K_ + k0 + gr * 8, &Bs[buf][ch * 8]);
    }
  };

  // tiles 0,1,2 (24 loads/thread-wave)
  stageA(0, 0); stageB(0, 0);
  stageA(1, 1); stageB(1, 1);
  stageA(2, 2); stageB(2, 2);
  __builtin_amdgcn_sched_barrier(0);

  // emb gather for t+1 (16 loads; depends on xiv — compiler inserts the wait)
  float ev[4][4];
#pragma unroll
  for (int m = 0; m < 4; ++m)
#pragma unroll
    for (int r = 0; r < 4; ++r)
      ev[m][r] = emb[(size_t)xiv[m][r] * E_ + e];
  __builtin_amdgcn_sched_barrier(0);

  // ---- fragment offsets (swizzled reads; 2-way residual = free) ----
  int aoff[2][4], boff[2][4];
#pragma unroll
  for (int ks = 0; ks < 2; ++ks) {
#pragma unroll
    for (int m = 0; m < 4; ++m) {
      int cl = (wr * 64 + m * 16 + lq) * 8 + ks * 4 + lh;
      aoff[ks][m] = (cl ^ ((cl >> 3) & 7)) * 8;
    }
#pragma unroll
    for (int n = 0; n < 4; ++n) {
      int cl = (wc * 64 + n * 16 + lq) * 8 + ks * 4 + lh;
      boff[ks][n] = (cl ^ ((cl >> 3) & 7)) * 8;
    }
  }

  f32x4 acc[4][4];
#pragma unroll
  for (int m = 0; m < 4; ++m)
#pragma unroll
    for (int n = 0; n < 4; ++n)
      acc[m][n] = (f32x4){0.f, 0.f, 0.f, 0.f};

  auto mfma_iter = [&](int rb) {
    const __hip_bfloat16* Ab = &As[rb][0];
    const __hip_bfloat16* Bb = &Bs[rb][0];
#pragma unroll
    for (int ks = 0; ks < 2; ++ks) {
      bfrag8 af[4], bfr[4];
#pragma unroll
      for (int m = 0; m < 4; ++m) af[m]  = *(const bfrag8*)(Ab + aoff[ks][m]);
#pragma unroll
      for (int n = 0; n < 4; ++n) bfr[n] = *(const bfrag8*)(Bb + boff[ks][n]);
      __builtin_amdgcn_s_setprio(1);
#pragma unroll
      for (int m = 0; m < 4; ++m)
#pragma unroll
        for (int n = 0; n < 4; ++n)
          acc[m][n] = __builtin_amdgcn_mfma_f32_16x16x32_bf16(af[m], bfr[n], acc[m][n], 0, 0, 0);
      __builtin_amdgcn_s_setprio(0);
    }
  };

#define SBAR() do { __builtin_amdgcn_s_barrier(); __builtin_amdgcn_sched_barrier(0); } while (0)

  // ---- counted-vmcnt pipeline, 16 iters, distance 3 ----
  // ledger (per wave, 8 loads/tile): prologue queue after emb =
  //   [cold+xiv+bg(36), t0(8), t1(8), t2(8), emb(16)]
  WAITVM(32); SBAR(); stageA(3, 3);  stageB(3, 3);  mfma_iter(0);  // t0 done
  WAITVM(32); SBAR(); stageA(4, 0);  stageB(4, 0);  mfma_iter(1);  // t1 done
  WAITVM(32); SBAR(); stageA(5, 1);  stageB(5, 1);  mfma_iter(2);  // t2 done
  WAITVM(16); SBAR(); stageA(6, 2);  stageB(6, 2);  mfma_iter(3);  // emb+t3 done
#pragma unroll 1
  for (int kt = 4; kt <= 12; ++kt) {
    WAITVM(16); SBAR();
    stageA(kt + 3, (kt + 3) & 3); stageB(kt + 3, (kt + 3) & 3);
    mfma_iter(kt & 3);
  }
  WAITVM(16); SBAR(); mfma_iter(1);   // t13
  WAITVM(8);  SBAR(); mfma_iter(2);   // t14
  WAITVM(0);  SBAR(); mfma_iter(3);   // t15
#undef SBAR

  // ---- register epilogue ----
  const bool last = (t == S_ - 1);
#pragma unroll
  for (int m = 0; m < 4; ++m) {
#pragma unroll
    for (int r = 0; r < 4; ++r) {
      int b = tm * BM + wr * 64 + m * 16 + lh * 4 + r;
      float iv = acc[m][0][r] + bg[0];
      float fv = acc[m][1][r] + bg[1];
      float gv = acc[m][2][r] + bg[2];
      float ov = acc[m][3][r] + bg[3];
      size_t cidx = (size_t)b * E_ + e;
      float ig = sigm(iv), fg = sigm(fv), gg = tanh_fast(gv), og = sigm(ov);
      float cn = fg * cold[m][r] + ig * gg;
      c[cidx] = cn;
      float h = og * tanh_fast(cn);
      if (last) {
        out[cidx] = h;
      } else {
        Anext[(size_t)b * K_ + E_ + e] = __float2bfloat16(h);
        Anext[(size_t)b * K_ + e]      = __float2bfloat16(ev[m][r]);
      }
    }
  }
}

extern "C" void kernel_launch(void* const* d_in, const int* in_sizes, int n_in,
                              void* d_out, int out_size, void* d_ws, size_t ws_size,
                              hipStream_t stream) {
  const int*   x   = (const int*)d_in[0];
  const float* emb = (const float*)d_in[1];
  const float* Wih = (const float*)d_in[2];
  const float* Whh = (const float*)d_in[3];
  const float* bih = (const float*)d_in[4];
  const float* bhh = (const float*)d_in[5];
  float* out = (float*)d_out;
  (void)in_sizes; (void)n_in; (void)out_size; (void)ws_size;

  char* p = (char*)d_ws;
  __hip_bfloat16* Wp    = (__hip_bfloat16*)p;  p += (size_t)NG * K_ * 2;  // 4 MB
  float*          biasP = (float*)p;           p += (size_t)NG * 4;       // 8 KB
  float*          c     = (float*)p;           p += (size_t)B_ * E_ * 4;  // 4 MB
  __hip_bfloat16* A0    = (__hip_bfloat16*)p;  p += (size_t)B_ * K_ * 2;  // 4 MB
  __hip_bfloat16* A1    = (__hip_bfloat16*)p;  p += (size_t)B_ * K_ * 2;  // 4 MB

  prep_weights<<<NG, 256, 0, stream>>>(Wih, Whh, bih, bhh, Wp, biasP);
  init_state<<<B_, 256, 0, stream>>>(x, emb, c, A0);
  for (int t = 0; t < S_; ++t) {
    __hip_bfloat16* Ac = (t & 1) ? A1 : A0;
    __hip_bfloat16* An = (t & 1) ? A0 : A1;
    lstm_step<<<256, 256, 0, stream>>>(Ac, An, Wp, biasP, c, x, emb, out, t);
  }
}